// Round 1
// baseline (799.522 us; speedup 1.0000x reference)
//
#include <hip/hip_runtime.h>

typedef unsigned short u16;
typedef __bf16 bf16x8 __attribute__((ext_vector_type(8)));
typedef float f32x4 __attribute__((ext_vector_type(4)));
typedef unsigned short u16x8 __attribute__((ext_vector_type(8)));

__device__ __forceinline__ u16 f2bf(float f) {
    unsigned u = __float_as_uint(f);
    u = (u + 0x7fffu + ((u >> 16) & 1u)) >> 16;
    return (u16)u;
}

// ---------------------------------------------------------------------------
// prep: bf16 weight conversions, weight transposes, C2 zero-init
// ranges: B1 442368 | B2 331776 | w_ihT 196608 | w_hhT 196608 | fi_wT 65536 | C2 1605632
// total 2838528 = 11088 * 256
// ---------------------------------------------------------------------------
__global__ __launch_bounds__(256) void prep_kernel(
    const float* __restrict__ cnn_w, const float* __restrict__ cnn1_w,
    const float* __restrict__ w_ih, const float* __restrict__ w_hh,
    const float* __restrict__ fi_w,
    u16* __restrict__ B1, u16* __restrict__ B2,
    float* __restrict__ w_ihT, float* __restrict__ w_hhT,
    float* __restrict__ fi_wT, float* __restrict__ C2)
{
    int idx = blockIdx.x * 256 + threadIdx.x;
    if (idx < 442368) { B1[idx] = f2bf(cnn_w[idx]); return; }
    idx -= 442368;
    if (idx < 331776) {
        // B2[n][off*576 + c] = cnn1_w[n][c][dy][dx], off = dy*3+dx
        int n = idx / 5184, rem = idx - n * 5184;
        int off = rem / 576, c = rem - off * 576;
        int dy = off / 3, dx = off - dy * 3;
        B2[idx] = f2bf(cnn1_w[((n * 576 + c) * 3 + dy) * 3 + dx]);
        return;
    }
    idx -= 331776;
    if (idx < 196608) { int k = idx / 768, g = idx - k * 768; w_ihT[idx] = w_ih[g * 256 + k]; return; }
    idx -= 196608;
    if (idx < 196608) { int k = idx / 768, g = idx - k * 768; w_hhT[idx] = w_hh[g * 256 + k]; return; }
    idx -= 196608;
    if (idx < 65536) { int k = idx / 256, j = idx - k * 256; fi_wT[idx] = fi_w[j * 256 + k]; return; }
    idx -= 65536;
    if (idx < 1605632) C2[idx] = 0.f;
}

// ---------------------------------------------------------------------------
// GEMM1: patchify conv as implicit-im2col MFMA GEMM
// C[m][n] = sum_k frames_patch[m][k] * cnn_w[n][k] + cnn_b[n], stored bf16 -> f1
// M=25088, K=768, N=576. Tiles: BM=128, BN=64, BK=64. grid.x = 196*9 (m-major swizzle)
// ---------------------------------------------------------------------------
__global__ __launch_bounds__(256) void gemm1_patchify(
    const float* __restrict__ frames, const u16* __restrict__ B1,
    const float* __restrict__ cnn_b, u16* __restrict__ f1)
{
    __shared__ u16 As[128 * 64];
    __shared__ u16 Bs[64 * 64];
    const int t = threadIdx.x;
    const int bx = blockIdx.x;
    const int m0 = (bx / 9) * 128;     // 9 consecutive blocks share same m-tile -> L2 reuse of frames
    const int n0 = (bx % 9) * 64;
    const int wave = t >> 6, lane = t & 63;
    const int lm = lane & 15, lq = lane >> 4;

    f32x4 acc[2][4];
#pragma unroll
    for (int i = 0; i < 2; ++i)
#pragma unroll
        for (int q = 0; q < 4; ++q) acc[i][q] = (f32x4){0.f, 0.f, 0.f, 0.f};

    // A staging: 1024 chunks of 8 bf16; 4 per thread; row fixed across k-tiles
    int arow[4], ac8[4], abase[4];
#pragma unroll
    for (int i = 0; i < 4; ++i) {
        int cid = t + i * 256;
        int row = cid >> 3, c8 = cid & 7;
        int m = m0 + row;
        int fr = m / 49, pos = m - fr * 49;
        int py = pos / 7, px = pos - py * 7;
        arow[i] = row; ac8[i] = c8;
        abase[i] = (fr * 3 * 112 + py * 16) * 112 + px * 16;
    }

    for (int kt = 0; kt < 12; ++kt) {
        const int k0 = kt * 64;
#pragma unroll
        for (int i = 0; i < 4; ++i) {
            int k = k0 + ac8[i] * 8;
            int c = k >> 8, dy = (k >> 4) & 15, dx = k & 15;
            const float* src = frames + abase[i] + (c * 112 + dy) * 112 + dx;
            float4 v0 = *(const float4*)src;
            float4 v1 = *(const float4*)(src + 4);
            u16x8 v = { f2bf(v0.x), f2bf(v0.y), f2bf(v0.z), f2bf(v0.w),
                        f2bf(v1.x), f2bf(v1.y), f2bf(v1.z), f2bf(v1.w) };
            int sidx = arow[i] * 8 + (ac8[i] ^ (arow[i] & 7));
            *(u16x8*)(&As[sidx * 8]) = v;
        }
#pragma unroll
        for (int i = 0; i < 2; ++i) {
            int cid = t + i * 256;
            int n = cid >> 3, c8 = cid & 7;
            u16x8 v = *(const u16x8*)(B1 + (size_t)(n0 + n) * 768 + k0 + c8 * 8);
            int sidx = n * 8 + (c8 ^ (n & 7));
            *(u16x8*)(&Bs[sidx * 8]) = v;
        }
        __syncthreads();
#pragma unroll
        for (int s = 0; s < 2; ++s) {
            bf16x8 a[2], b[4];
#pragma unroll
            for (int mi = 0; mi < 2; ++mi) {
                int row = wave * 32 + mi * 16 + lm;
                int c8 = s * 4 + lq;
                a[mi] = *(const bf16x8*)(&As[(row * 8 + (c8 ^ (row & 7))) * 8]);
            }
#pragma unroll
            for (int q = 0; q < 4; ++q) {
                int n = q * 16 + lm;
                int c8 = s * 4 + lq;
                b[q] = *(const bf16x8*)(&Bs[(n * 8 + (c8 ^ (n & 7))) * 8]);
            }
#pragma unroll
            for (int mi = 0; mi < 2; ++mi)
#pragma unroll
                for (int q = 0; q < 4; ++q)
                    acc[mi][q] = __builtin_amdgcn_mfma_f32_16x16x32_bf16(a[mi], b[q], acc[mi][q], 0, 0, 0);
        }
        __syncthreads();
    }
    // epilogue: + bias, -> bf16 f1[m][n]  (C/D layout: m = lq*4+r, n = lm)
#pragma unroll
    for (int mi = 0; mi < 2; ++mi) {
#pragma unroll
        for (int q = 0; q < 4; ++q) {
            int n = n0 + q * 16 + lm;
            float bias = cnn_b[n];
#pragma unroll
            for (int r = 0; r < 4; ++r) {
                int m = m0 + wave * 32 + mi * 16 + lq * 4 + r;
                f1[(size_t)m * 576 + n] = f2bf(acc[mi][q][r] + bias);
            }
        }
    }
}

// ---------------------------------------------------------------------------
// GEMM2: 3x3 SAME conv as 9-offset implicit GEMM over f1 (NHWC per frame, 7x7)
// M=25088, K=5184 (= 9 offsets * 576ch), N=64. BM=64, BK=64, K split x3 -> atomicAdd
// grid.x = 392*3 (m-major swizzle: 3 k-chunk blocks adjacent -> share f1 in L2)
// ---------------------------------------------------------------------------
__global__ __launch_bounds__(256) void gemm2_conv1(
    const u16* __restrict__ f1, const u16* __restrict__ B2,
    float* __restrict__ C2)
{
    __shared__ u16 As[64 * 64];
    __shared__ u16 Bs[64 * 64];
    const int t = threadIdx.x;
    const int bx = blockIdx.x;
    const int m0 = (bx / 3) * 64;
    const int ktbase = (bx % 3) * 27;
    const int wave = t >> 6, lane = t & 63;
    const int lm = lane & 15, lq = lane >> 4;

    f32x4 acc[4];
#pragma unroll
    for (int q = 0; q < 4; ++q) acc[q] = (f32x4){0.f, 0.f, 0.f, 0.f};

    int arow[2], ac8[2], afr[2], apy[2], apx[2];
#pragma unroll
    for (int i = 0; i < 2; ++i) {
        int cid = t + i * 256;
        int row = cid >> 3, c8 = cid & 7;
        int m = m0 + row;
        int fr = m / 49, pos = m - fr * 49;
        int py = pos / 7;
        arow[i] = row; ac8[i] = c8; afr[i] = fr; apy[i] = py; apx[i] = pos - py * 7;
    }

    for (int kk = 0; kk < 27; ++kk) {
        int kt = ktbase + kk;
        int off = kt / 9, cb = kt - off * 9;
        int dy = off / 3, dx = off - dy * 3;   // 0..2 each; spatial shift dy-1, dx-1
        int c0 = cb * 64;
#pragma unroll
        for (int i = 0; i < 2; ++i) {
            int yy = apy[i] + dy - 1, xx = apx[i] + dx - 1;
            u16x8 v = {};
            if ((unsigned)yy < 7u && (unsigned)xx < 7u)
                v = *(const u16x8*)(f1 + ((size_t)(afr[i] * 49 + yy * 7 + xx)) * 576 + c0 + ac8[i] * 8);
            *(u16x8*)(&As[(arow[i] * 8 + (ac8[i] ^ (arow[i] & 7))) * 8]) = v;
        }
#pragma unroll
        for (int i = 0; i < 2; ++i) {
            int cid = t + i * 256;
            int n = cid >> 3, c8 = cid & 7;
            u16x8 v = *(const u16x8*)(B2 + (size_t)n * 5184 + kt * 64 + c8 * 8);
            *(u16x8*)(&Bs[(n * 8 + (c8 ^ (n & 7))) * 8]) = v;
        }
        __syncthreads();
#pragma unroll
        for (int s = 0; s < 2; ++s) {
            int row = wave * 16 + lm;
            int c8 = s * 4 + lq;
            bf16x8 a = *(const bf16x8*)(&As[(row * 8 + (c8 ^ (row & 7))) * 8]);
            bf16x8 b[4];
#pragma unroll
            for (int q = 0; q < 4; ++q) {
                int n = q * 16 + lm;
                b[q] = *(const bf16x8*)(&Bs[(n * 8 + (c8 ^ (n & 7))) * 8]);
            }
#pragma unroll
            for (int q = 0; q < 4; ++q)
                acc[q] = __builtin_amdgcn_mfma_f32_16x16x32_bf16(a, b[q], acc[q], 0, 0, 0);
        }
        __syncthreads();
    }
#pragma unroll
    for (int q = 0; q < 4; ++q)
#pragma unroll
        for (int r = 0; r < 4; ++r) {
            int m = m0 + wave * 16 + lq * 4 + r;
            int n = q * 16 + lm;
            atomicAdd(&C2[(size_t)m * 64 + n], acc[q][r]);
        }
}

// ---------------------------------------------------------------------------
// reduce: f[bl][ch] = BN( mean_p relu(C2[bl*49+p][ch] + cnn1_b[ch]) )
// (BN affine commutes with the mean)
// ---------------------------------------------------------------------------
__global__ __launch_bounds__(256) void reduce_kernel(
    const float* __restrict__ C2, const float* __restrict__ cnn1_b,
    const float* __restrict__ bn_g, const float* __restrict__ bn_b,
    const float* __restrict__ bn_m, const float* __restrict__ bn_v,
    float* __restrict__ fmean)
{
    int idx = blockIdx.x * 256 + threadIdx.x;  // 32768 = 512*64
    int bl = idx >> 6, ch = idx & 63;
    float bias = cnn1_b[ch];
    const float* p = C2 + (size_t)bl * 49 * 64 + ch;
    float s = 0.f;
#pragma unroll
    for (int i = 0; i < 49; ++i) s += fmaxf(p[i * 64] + bias, 0.f);
    float mean = s * (1.f / 49.f);
    float inv = bn_g[ch] * rsqrtf(bn_v[ch] + 1e-5f);
    fmean[idx] = (mean - bn_m[ch]) * inv + bn_b[ch];
}

// ---------------------------------------------------------------------------
// rnn: adapters + GRU encoder (16 steps) + AR decoder (10 steps), fp32
// one block per batch sample, 256 threads (one per hidden unit)
// ---------------------------------------------------------------------------
__global__ __launch_bounds__(256) void rnn_kernel(
    const float* __restrict__ x, const float* __restrict__ fmean,
    const float* __restrict__ a0_w, const float* __restrict__ a0_b,
    const float* __restrict__ ai_w, const float* __restrict__ ai_b,
    const float* __restrict__ an_w, const float* __restrict__ an_b,
    const float* __restrict__ w_ihT, const float* __restrict__ w_hhT,
    const float* __restrict__ b_ih, const float* __restrict__ b_hh,
    const float* __restrict__ fi_wT, const float* __restrict__ fi_b,
    const float* __restrict__ fn_w, const float* __restrict__ fn_b,
    float* __restrict__ out)
{
    const int b = blockIdx.x, t = threadIdx.x;
    __shared__ float zx[16][256];
    __shared__ float sf[80];
    __shared__ float s0[16];
    __shared__ float h[256];
    __shared__ float xr[256];

    // adapters: s = relu(x@a0^T+b); s += relu(s@ai^T+b); concat [s, f]; zx = relu(@an^T+b)
    for (int l = 0; l < 16; ++l) {
        if (t < 16) {
            float a = a0_b[t];
            const float* xp = x + (b * 16 + l) * 12;
#pragma unroll
            for (int i = 0; i < 12; ++i) a += xp[i] * a0_w[t * 12 + i];
            s0[t] = fmaxf(a, 0.f);
        }
        __syncthreads();
        if (t < 16) {
            float a = ai_b[t];
#pragma unroll
            for (int i = 0; i < 16; ++i) a += s0[i] * ai_w[t * 16 + i];
            sf[t] = s0[t] + fmaxf(a, 0.f);
        } else if (t < 80) {
            sf[t] = fmean[(b * 16 + l) * 64 + (t - 16)];
        }
        __syncthreads();
        float a = an_b[t];
#pragma unroll 8
        for (int i = 0; i < 80; ++i) a += sf[i] * an_w[t * 80 + i];
        zx[l][t] = fmaxf(a, 0.f);
        __syncthreads();
    }

    h[t] = 0.f;
    __syncthreads();
    const float bir = b_ih[t], biz = b_ih[256 + t], bin_ = b_ih[512 + t];
    const float bhr = b_hh[t], bhz = b_hh[256 + t], bhn = b_hh[512 + t];

    // encoder
    for (int l = 0; l < 16; ++l) {
        float gir = bir, giz = biz, gin = bin_;
        float ghr = bhr, ghz = bhz, ghn = bhn;
        const float* xt = zx[l];
#pragma unroll 4
        for (int k = 0; k < 256; ++k) {
            float xk = xt[k], hk = h[k];
            const float* wi = w_ihT + k * 768 + t;
            const float* wh = w_hhT + k * 768 + t;
            gir += xk * wi[0]; giz += xk * wi[256]; gin += xk * wi[512];
            ghr += hk * wh[0]; ghz += hk * wh[256]; ghn += hk * wh[512];
        }
        float r = 1.f / (1.f + expf(-(gir + ghr)));
        float z = 1.f / (1.f + expf(-(giz + ghz)));
        float n = tanhf(gin + r * ghn);
        float hnew = (1.f - z) * n + z * h[t];
        __syncthreads();
        h[t] = hnew;
        __syncthreads();
    }

    // decoder
    xr[t] = h[t];
    __syncthreads();
    for (int st = 0; st < 10; ++st) {
        float gir = bir, giz = biz, gin = bin_;
        float ghr = bhr, ghz = bhz, ghn = bhn;
#pragma unroll 4
        for (int k = 0; k < 256; ++k) {
            float xk = xr[k], hk = h[k];
            const float* wi = w_ihT + k * 768 + t;
            const float* wh = w_hhT + k * 768 + t;
            gir += xk * wi[0]; giz += xk * wi[256]; gin += xk * wi[512];
            ghr += hk * wh[0]; ghz += hk * wh[256]; ghn += hk * wh[512];
        }
        float r = 1.f / (1.f + expf(-(gir + ghr)));
        float z = 1.f / (1.f + expf(-(giz + ghz)));
        float n = tanhf(gin + r * ghn);
        float hnew = (1.f - z) * n + z * h[t];
        __syncthreads();
        h[t] = hnew;          // h = hn
        __syncthreads();
        float a = fi_b[t];
#pragma unroll 4
        for (int k = 0; k < 256; ++k) a += h[k] * fi_wT[k * 256 + t];
        float xnew = h[t] + fmaxf(a, 0.f);
        __syncthreads();
        xr[t] = xnew;         // xi = xr
        __syncthreads();
        if (t < 2) {
            float a2 = fn_b[t];
            for (int k = 0; k < 256; ++k) a2 += xr[k] * fn_w[t * 256 + k];
            out[st * 64 + b * 2 + t] = tanhf(a2);   // (10, 32, 1, 2)
        }
    }
}

// ---------------------------------------------------------------------------
extern "C" void kernel_launch(void* const* d_in, const int* in_sizes, int n_in,
                              void* d_out, int out_size, void* d_ws, size_t ws_size,
                              hipStream_t stream)
{
    const float* x      = (const float*)d_in[0];
    const float* frames = (const float*)d_in[1];
    const float* cnn_w  = (const float*)d_in[2];
    const float* cnn_b  = (const float*)d_in[3];
    const float* cnn1_w = (const float*)d_in[4];
    const float* cnn1_b = (const float*)d_in[5];
    const float* bn_g   = (const float*)d_in[6];
    const float* bn_b   = (const float*)d_in[7];
    const float* bn_m   = (const float*)d_in[8];
    const float* bn_v   = (const float*)d_in[9];
    const float* a0_w   = (const float*)d_in[10];
    const float* a0_b   = (const float*)d_in[11];
    const float* ai_w   = (const float*)d_in[12];
    const float* ai_b   = (const float*)d_in[13];
    const float* an_w   = (const float*)d_in[14];
    const float* an_b   = (const float*)d_in[15];
    const float* w_ih   = (const float*)d_in[16];
    const float* w_hh   = (const float*)d_in[17];
    const float* b_ih   = (const float*)d_in[18];
    const float* b_hh   = (const float*)d_in[19];
    const float* fi_w   = (const float*)d_in[20];
    const float* fi_b   = (const float*)d_in[21];
    const float* fn_w   = (const float*)d_in[22];
    const float* fn_b   = (const float*)d_in[23];
    float* out = (float*)d_out;

    char* ws = (char*)d_ws;
    u16*   f1    = (u16*)(ws);                  // 25088*576*2 = 28,901,376
    u16*   B1    = (u16*)(ws + 28901376);       //   884,736
    u16*   B2    = (u16*)(ws + 29786112);       //   663,552
    float* C2    = (float*)(ws + 30449664);     // 6,422,528
    float* fmean = (float*)(ws + 36872192);     //   131,072
    float* w_ihT = (float*)(ws + 37003264);     //   786,432
    float* w_hhT = (float*)(ws + 37789696);     //   786,432
    float* fi_wT = (float*)(ws + 38576128);     //   262,144
    // total 38,838,272 bytes

    prep_kernel<<<11088, 256, 0, stream>>>(cnn_w, cnn1_w, w_ih, w_hh, fi_w,
                                           B1, B2, w_ihT, w_hhT, fi_wT, C2);
    gemm1_patchify<<<196 * 9, 256, 0, stream>>>(frames, B1, cnn_b, f1);
    gemm2_conv1<<<392 * 3, 256, 0, stream>>>(f1, B2, C2);
    reduce_kernel<<<128, 256, 0, stream>>>(C2, cnn1_b, bn_g, bn_b, bn_m, bn_v, fmean);
    rnn_kernel<<<32, 256, 0, stream>>>(x, fmean, a0_w, a0_b, ai_w, ai_b, an_w, an_b,
                                       w_ihT, w_hhT, b_ih, b_hh, fi_wT, fi_b, fn_w, fn_b, out);
}